// Round 7
// baseline (165.238 us; speedup 1.0000x reference)
//
#include <hip/hip_runtime.h>

// LaplacianLoss on a fixed 512x512 grid mesh, B=32.
// Lv[b,(i,j)] = v - (1/deg)*sum(nbrs), nbrs = (i,j+-1),(i+-1,j),(i-1,j+1),(i+1,j-1)
// out = mean over (B,V) of |Lv|^2.
//
// R6 lesson: block-wide LDS staging forces a barrier per row; LDS pipe
// (~16us, 4-way-conflicted scalar reads) and HBM (~17us) serialize -> ~37us.
// R7: no LDS, no barriers. Each wave owns a 128-col strip; thread owns col
// pair (E,O); horizontal neighbors via intra-wave shuffles (+2 predicated
// edge-lane halo loads). T/M/C combos carried in 24 regs (R6 math, verified);
// #pragma unroll 2 renames the rotation without R3's VGPR blowup.

#define GH 512
#define GW 512
#define GV (GH * GW)
#define ROWF (GW * 3)            // 1536 floats per row
#define RI 8                     // center rows per block
#define NCHUNK (GH / RI)         // 64
#define NITER (RI + 2)           // 10
#define NBLK (32 * NCHUNK)       // 2048 blocks

__global__ __launch_bounds__(256, 6) void lap_partial_kernel(
    const float* __restrict__ verts, float* __restrict__ partials) {
    const int bid   = blockIdx.x;
    const int batch = bid >> 6;
    const int chunk = bid & (NCHUNK - 1);
    const int i0    = chunk * RI;
    const int p     = threadIdx.x;          // col-pair index: cols 2p, 2p+1
    const int lane  = p & 63;
    const float* __restrict__ pcol = verts + (size_t)batch * (GV * 3) + 6 * p;

    const float jle = (p > 0)   ? 1.f : 0.f;   // even col 2p has left nbr
    const float jro = (p < 255) ? 1.f : 0.f;   // odd col 2p+1 has right nbr
    const float invE_m = -1.f / (4.f + 2.f * jle);
    const float invO_m = -1.f / (4.f + 2.f * jro);
    const float invE_t = -1.f / (2.f + 2.f * jle);
    const float invO_t = -1.f / (3.f + jro);
    const float invE_b = -1.f / (3.f + jle);
    const float invO_b = -1.f / (2.f + 2.f * jro);

    // carried combos (R6 timeline): T2=T(c-1), T1=T(c), M1=M(c), C1=C(c)
    float T2Ex=0,T2Ey=0,T2Ez=0, T2Ox=0,T2Oy=0,T2Oz=0;
    float T1Ex=0,T1Ey=0,T1Ez=0, T1Ox=0,T1Oy=0,T1Oz=0;
    float M1Ex=0,M1Ey=0,M1Ez=0, M1Ox=0,M1Oy=0,M1Oz=0;
    float C1Ex=0,C1Ey=0,C1Ez=0, C1Ox=0,C1Oy=0,C1Oz=0;
    float local = 0.f;

    #pragma unroll 2
    for (int k = 0; k < NITER; ++k) {
        const int r = i0 - 1 + k;           // row being consumed this iter

        float Ex=0,Ey=0,Ez=0, Ox=0,Oy=0,Oz=0;
        float hlx=0,hly=0,hlz=0, hrx=0,hry=0,hrz=0;
        if (r >= 0 && r < GH) {             // block-uniform branch
            const float* __restrict__ rp = pcol + (size_t)r * ROWF;
            Ex = rp[0]; Ey = rp[1]; Ez = rp[2];
            Ox = rp[3]; Oy = rp[4]; Oz = rp[5];
            if (lane == 0 && p > 0) {       // strip-left halo col 2p-1
                hlx = rp[-3]; hly = rp[-2]; hlz = rp[-1];
            }
            if (lane == 63 && p < 255) {    // strip-right halo col 2p+2
                hrx = rp[6]; hry = rp[7]; hrz = rp[8];
            }
        }

        // horizontal neighbors: L = col 2p-1 (O of pair p-1), R = col 2p+2
        float Lx = __shfl_up(Ox, 1, 64), Ly = __shfl_up(Oy, 1, 64), Lz = __shfl_up(Oz, 1, 64);
        float Rx = __shfl_down(Ex, 1, 64), Ry = __shfl_down(Ey, 1, 64), Rz = __shfl_down(Ez, 1, 64);
        if (lane == 0)  { Lx = hlx; Ly = hly; Lz = hlz; }   // p==0 -> 0 (masked)
        if (lane == 63) { Rx = hrx; Ry = hry; Rz = hrz; }   // p==255 -> 0

        // combos for row r:  B = C+L, T = C+R, M = L+R  (per col pair E/O)
        const float BnEx = Ex + Lx, BnEy = Ey + Ly, BnEz = Ez + Lz;
        const float BnOx = Ox + Ex, BnOy = Oy + Ey, BnOz = Oz + Ez;
        const float TnEx = Ex + Ox, TnEy = Ey + Oy, TnEz = Ez + Oz;
        const float TnOx = Ox + Rx, TnOy = Oy + Ry, TnOz = Oz + Rz;
        const float MnEx = Lx + Ox, MnEy = Ly + Oy, MnEz = Lz + Oz;
        const float MnOx = Ex + Rx, MnOy = Ey + Ry, MnOz = Ez + Rz;

        // finalize center c = r-1: sum = T(c-1) + M(c) + B(c+1)
        if (k >= 2) {
            const int c = i0 + k - 2;
            float invE = invE_m, invO = invO_m;
            if (c == 0)           { invE = invE_t; invO = invO_t; }
            else if (c == GH - 1) { invE = invE_b; invO = invO_b; }

            float s, lv;
            s = T2Ex + M1Ex + BnEx; lv = fmaf(invE, s, C1Ex); local = fmaf(lv, lv, local);
            s = T2Ey + M1Ey + BnEy; lv = fmaf(invE, s, C1Ey); local = fmaf(lv, lv, local);
            s = T2Ez + M1Ez + BnEz; lv = fmaf(invE, s, C1Ez); local = fmaf(lv, lv, local);
            s = T2Ox + M1Ox + BnOx; lv = fmaf(invO, s, C1Ox); local = fmaf(lv, lv, local);
            s = T2Oy + M1Oy + BnOy; lv = fmaf(invO, s, C1Oy); local = fmaf(lv, lv, local);
            s = T2Oz + M1Oz + BnOz; lv = fmaf(invO, s, C1Oz); local = fmaf(lv, lv, local);
        }

        // rotate: T2<-T1, T1<-Tn, M1<-Mn, C1<-Cn (renamed by unroll)
        T2Ex = T1Ex; T2Ey = T1Ey; T2Ez = T1Ez; T2Ox = T1Ox; T2Oy = T1Oy; T2Oz = T1Oz;
        T1Ex = TnEx; T1Ey = TnEy; T1Ez = TnEz; T1Ox = TnOx; T1Oy = TnOy; T1Oz = TnOz;
        M1Ex = MnEx; M1Ey = MnEy; M1Ez = MnEz; M1Ox = MnOx; M1Oy = MnOy; M1Oz = MnOz;
        C1Ex = Ex;   C1Ey = Ey;   C1Ez = Ez;   C1Ox = Ox;   C1Oy = Oy;   C1Oz = Oz;
    }

    // block reduction: wave shuffle -> LDS -> one store per block
    #pragma unroll
    for (int off = 32; off > 0; off >>= 1)
        local += __shfl_down(local, off, 64);

    __shared__ float wsum[4];
    const int wave = p >> 6;
    if (lane == 0) wsum[wave] = local;
    __syncthreads();
    if (p == 0)
        partials[bid] = wsum[0] + wsum[1] + wsum[2] + wsum[3];
}

__global__ __launch_bounds__(256) void lap_final_kernel(
    const float* __restrict__ partials, float* __restrict__ out, int nblk, int B) {
    float local = 0.0f;
    for (int k = threadIdx.x; k < nblk; k += 256)
        local += partials[k];

    #pragma unroll
    for (int off = 32; off > 0; off >>= 1)
        local += __shfl_down(local, off, 64);

    __shared__ float wsum[4];
    const int lane = threadIdx.x & 63;
    const int wid  = threadIdx.x >> 6;
    if (lane == 0) wsum[wid] = local;
    __syncthreads();

    if (threadIdx.x == 0) {
        const float s = wsum[0] + wsum[1] + wsum[2] + wsum[3];
        out[0] = s / ((float)B * (float)GV);
    }
}

extern "C" void kernel_launch(void* const* d_in, const int* in_sizes, int n_in,
                              void* d_out, int out_size, void* d_ws, size_t ws_size,
                              hipStream_t stream) {
    const float* verts = (const float*)d_in[0];
    float* out = (float*)d_out;
    float* partials = (float*)d_ws;            // 2048 floats = 8 KB

    const int B = in_sizes[0] / (GV * 3);      // 32

    lap_partial_kernel<<<NBLK, 256, 0, stream>>>(verts, partials);
    lap_final_kernel<<<1, 256, 0, stream>>>(partials, out, NBLK, B);
}

// Round 8
// 165.064 us; speedup vs baseline: 1.0011x; 1.0011x over previous
//
#include <hip/hip_runtime.h>

// LaplacianLoss on a fixed 512x512 grid mesh, B=32.
// Lv[b,(i,j)] = v - (1/deg)*sum(nbrs), nbrs = (i,j+-1),(i+-1,j),(i-1,j+1),(i+1,j-1)
// out = mean over (B,V) of |Lv|^2.
//
// R8 insight: in flattened row space (1536 floats), all horizontal/diagonal
// neighbors are q+-3; vertical are same-q in adjacent rows. Thread owns one
// float4 of the row (perfectly coalesced, 1x L1 line-touch), shifted vectors
// Qm3/Qp3 built from 8 one-lane shuffles. No LDS staging, no barriers, no
// strided reads. T/B/M combo carry identical to verified R6 math.

#define GH 512
#define GW 512
#define GV (GH * GW)
#define ROWF 1536                // floats per row
#define RQ 384                   // float4s per row = threads per block
#define RI 16                    // center rows per block
#define NCHUNK (GH / RI)         // 32
#define NITER (RI + 2)           // 18
#define NBLK (32 * NCHUNK)       // 1024 blocks

__global__ __launch_bounds__(RQ, 6) void lap_partial_kernel(
    const float* __restrict__ verts, float* __restrict__ partials) {
    const int bid   = blockIdx.x;
    const int batch = bid >> 5;
    const int chunk = bid & 31;
    const int i0    = chunk * RI;
    const int t     = threadIdx.x;       // owns floats [4t, 4t+4) of each row
    const int lane  = t & 63;
    const float* __restrict__ base = verts + (size_t)batch * (GV * 3) + 4 * t;

    // per-element -1/deg for mid/top/bottom row regimes
    float invM[4], invT[4], invB[4];
    #pragma unroll
    for (int e = 0; e < 4; ++e) {
        const int q = 4 * t + e;
        const float jl = (q >= 3) ? 1.f : 0.f;         // col > 0
        const float jr = (q < ROWF - 3) ? 1.f : 0.f;   // col < 511
        invM[e] = -1.f / (2.f + 2.f * jl + 2.f * jr);
        invT[e] = -1.f / (1.f + 2.f * jl + jr);
        invB[e] = -1.f / (1.f + jl + 2.f * jr);
    }
    const bool needHL = (lane == 0)  && (t > 0);       // f[4t-3..4t)
    const bool needHR = (lane == 63) && (t < RQ - 1);  // f[4t+4..4t+7)

    // prefetch row i0-1
    float4 qn = make_float4(0.f, 0.f, 0.f, 0.f);
    float nhl0 = 0, nhl1 = 0, nhl2 = 0, nhr0 = 0, nhr1 = 0, nhr2 = 0;
    if (i0 > 0) {
        const float* rp = base + (size_t)(i0 - 1) * ROWF;
        qn = *(const float4*)rp;
        if (needHL) { nhl0 = rp[-3]; nhl1 = rp[-2]; nhl2 = rp[-1]; }
        if (needHR) { nhr0 = rp[4];  nhr1 = rp[5];  nhr2 = rp[6]; }
    }

    // carried combos: T2=T(c-1), T1=T(c), M1=M(c), C1=Q(c)
    float4 T2 = make_float4(0,0,0,0), T1 = T2, M1 = T2, C1 = T2;
    float local = 0.f;

    #pragma unroll 2
    for (int k = 0; k < NITER; ++k) {
        const float4 Q = qn;
        const float chl0 = nhl0, chl1 = nhl1, chl2 = nhl2;
        const float chr0 = nhr0, chr1 = nhr1, chr2 = nhr2;

        // prefetch row i0+k for next iter
        nhl0 = 0; nhl1 = 0; nhl2 = 0; nhr0 = 0; nhr1 = 0; nhr2 = 0;
        const int rn = i0 + k;
        if (k < NITER - 1 && rn < GH) {
            const float* rp = base + (size_t)rn * ROWF;
            qn = *(const float4*)rp;
            if (needHL) { nhl0 = rp[-3]; nhl1 = rp[-2]; nhl2 = rp[-1]; }
            if (needHR) { nhr0 = rp[4];  nhr1 = rp[5];  nhr2 = rp[6]; }
        } else {
            qn = make_float4(0.f, 0.f, 0.f, 0.f);
        }

        // shifted vectors via one-lane shuffles (wave-internal, no sync)
        const float py = __shfl_up(Q.y, 1, 64);
        const float pz = __shfl_up(Q.z, 1, 64);
        const float pw = __shfl_up(Q.w, 1, 64);
        const float nx = __shfl_down(Q.x, 1, 64);
        const float ny = __shfl_down(Q.y, 1, 64);
        const float nz = __shfl_down(Q.z, 1, 64);

        float4 Qm3, Qp3;                  // f[q-3], f[q+3] per element
        Qm3.x = (lane == 0)  ? chl0 : py; // t==0 -> 0 (left grid edge masked)
        Qm3.y = (lane == 0)  ? chl1 : pz;
        Qm3.z = (lane == 0)  ? chl2 : pw;
        Qm3.w = Q.x;
        Qp3.x = Q.w;
        Qp3.y = (lane == 63) ? chr0 : nx; // t==RQ-1 -> 0 (right edge masked)
        Qp3.z = (lane == 63) ? chr1 : ny;
        Qp3.w = (lane == 63) ? chr2 : nz;

        // combos for row n: B = Q+Qm3 (to row above), T = Q+Qp3 (to row below),
        // M = Qm3+Qp3 (own row)
        float4 Bn, Tn, Mn;
        Bn.x = Q.x + Qm3.x; Bn.y = Q.y + Qm3.y; Bn.z = Q.z + Qm3.z; Bn.w = Q.w + Qm3.w;
        Tn.x = Q.x + Qp3.x; Tn.y = Q.y + Qp3.y; Tn.z = Q.z + Qp3.z; Tn.w = Q.w + Qp3.w;
        Mn.x = Qm3.x + Qp3.x; Mn.y = Qm3.y + Qp3.y; Mn.z = Qm3.z + Qp3.z; Mn.w = Qm3.w + Qp3.w;

        // finalize center c = i0+k-2: S = T(c-1) + M(c) + B(c+1)
        if (k >= 2) {
            const int c = i0 + k - 2;
            const float* inv = invM;
            if (c == 0) inv = invT;
            else if (c == GH - 1) inv = invB;

            float s, lv;
            s = T2.x + M1.x + Bn.x; lv = fmaf(inv[0], s, C1.x); local = fmaf(lv, lv, local);
            s = T2.y + M1.y + Bn.y; lv = fmaf(inv[1], s, C1.y); local = fmaf(lv, lv, local);
            s = T2.z + M1.z + Bn.z; lv = fmaf(inv[2], s, C1.z); local = fmaf(lv, lv, local);
            s = T2.w + M1.w + Bn.w; lv = fmaf(inv[3], s, C1.w); local = fmaf(lv, lv, local);
        }

        // rotate
        T2 = T1; T1 = Tn; M1 = Mn; C1 = Q;
    }

    // block reduction: wave shuffle -> LDS -> one store per block
    #pragma unroll
    for (int off = 32; off > 0; off >>= 1)
        local += __shfl_down(local, off, 64);

    __shared__ float wsum[6];
    const int wave = t >> 6;
    if (lane == 0) wsum[wave] = local;
    __syncthreads();
    if (t == 0) {
        float s = wsum[0];
        #pragma unroll
        for (int w = 1; w < 6; ++w) s += wsum[w];
        partials[bid] = s;
    }
}

__global__ __launch_bounds__(256) void lap_final_kernel(
    const float* __restrict__ partials, float* __restrict__ out, int nblk, int B) {
    float local = 0.0f;
    for (int k = threadIdx.x; k < nblk; k += 256)
        local += partials[k];

    #pragma unroll
    for (int off = 32; off > 0; off >>= 1)
        local += __shfl_down(local, off, 64);

    __shared__ float wsum[4];
    const int lane = threadIdx.x & 63;
    const int wid  = threadIdx.x >> 6;
    if (lane == 0) wsum[wid] = local;
    __syncthreads();

    if (threadIdx.x == 0) {
        const float s = wsum[0] + wsum[1] + wsum[2] + wsum[3];
        out[0] = s / ((float)B * (float)GV);
    }
}

extern "C" void kernel_launch(void* const* d_in, const int* in_sizes, int n_in,
                              void* d_out, int out_size, void* d_ws, size_t ws_size,
                              hipStream_t stream) {
    const float* verts = (const float*)d_in[0];
    float* out = (float*)d_out;
    float* partials = (float*)d_ws;            // 1024 floats = 4 KB

    const int B = in_sizes[0] / (GV * 3);      // 32

    lap_partial_kernel<<<NBLK, RQ, 0, stream>>>(verts, partials);
    lap_final_kernel<<<1, 256, 0, stream>>>(partials, out, NBLK, B);
}